// Round 1
// baseline (319.898 us; speedup 1.0000x reference)
//
#include <hip/hip_runtime.h>
#include <hip/hip_bf16.h>

#define CDIV(a,b) (((a)+(b)-1)/(b))

typedef __bf16 bf16x8 __attribute__((ext_vector_type(8)));
typedef float  f32x4  __attribute__((ext_vector_type(4)));

union Frag16 { uint4 u; bf16x8 f; unsigned short s[8]; };
union Pack8  { unsigned short s[4]; uint2 u; };

__device__ __forceinline__ unsigned short f2bf(float f) {   // fp32 -> bf16 RNE
    unsigned u = __float_as_uint(f);
    return (unsigned short)((u + 0x7fff + ((u >> 16) & 1)) >> 16);
}
__device__ __forceinline__ float bf2f(unsigned short s) {
    return __uint_as_float(((unsigned)s) << 16);
}

__device__ __forceinline__ int load_src(const int* e, int f, int E, int i) {
    return f ? e[i] : e[2 * i];
}
__device__ __forceinline__ int load_dst(const int* e, int f, int E, int i) {
    return f ? e[E + i] : e[2 * (E + i)];
}

// ---------------------------------------------------------------------------
// prep: blocks 0,1 swizzle W1/W2 -> hi/lo bf16 MFMA B-fragments; block 2
// zeroes flag then samples edge layout (int64 LE => odd words all zero);
// blocks >=3 zero counts_sh (replaces the hipMemsetAsync dispatch).
// Fragment order: chunk c=(ntile*4+ks)*64+lane, 8 bf16:
//   B[k = ks*32 + (lane>>4)*8 + j][n = ntile*16 + (lane&15)]
// ---------------------------------------------------------------------------
__global__ __launch_bounds__(256) void prep_kernel(const float* __restrict__ W1,
                                                   const float* __restrict__ W2,
                                                   unsigned short* __restrict__ Wf1h,
                                                   unsigned short* __restrict__ Wf1l,
                                                   unsigned short* __restrict__ Wf2h,
                                                   unsigned short* __restrict__ Wf2l,
                                                   const int* __restrict__ edges,
                                                   int* __restrict__ flag, int E,
                                                   int4* __restrict__ zero_base, int Z4) {
    int tid = threadIdx.x;
    if (blockIdx.x == 2) {
        if (tid == 0) *flag = 0;
        __syncthreads();
        int n = min(E, 4096);
        int found = 0;
        for (int j = tid; j < n; j += 256) found |= (edges[2 * j + 1] != 0);
        if (found) *flag = 1;   // benign race within block
        return;
    }
    if (blockIdx.x >= 3) {
        int idx = (blockIdx.x - 3) * 256 + tid;
        if (idx < Z4) zero_base[idx] = make_int4(0, 0, 0, 0);
        return;
    }
    const float* W = (blockIdx.x == 0) ? W1 : W2;
    unsigned short* Wfh = (blockIdx.x == 0) ? Wf1h : Wf2h;
    unsigned short* Wfl = (blockIdx.x == 0) ? Wf1l : Wf2l;
    #pragma unroll
    for (int it = 0; it < 8; ++it) {
        int c = it * 256 + tid;           // chunk in [0, 2048)
        int ntk = c >> 6;
        int lane = c & 63;
        int ks = ntk & 3;
        int ntile = ntk >> 2;
        int quad = lane >> 4, nlo = lane & 15;
        int n = ntile * 16 + nlo;
        Frag16 h, l;
        #pragma unroll
        for (int j = 0; j < 8; ++j) {
            float w = W[(ks * 32 + quad * 8 + j) * 128 + n];
            h.s[j] = f2bf(w);
            float rr = w - bf2f(h.s[j]);
            l.s[j] = f2bf(rr);
        }
        *(uint4*)(Wfh + (size_t)c * 8) = h.u;
        *(uint4*)(Wfl + (size_t)c * 8) = l.u;
    }
}

// ---------------------------------------------------------------------------
// Split-bf16 MFMA GEMM body (fp32 input): out16 = bf16( X @ W ), fp32-accurate
// via xh*wh + xh*wl + xl*wh.  64 rows/block, 4 waves.
// C-write is QUARTER-BLOCKED: out16 layout [4][N][32] so the downstream
// gather kernel's 64B/node slices are CONTIGUOUS (L2-set-friendly).
// ---------------------------------------------------------------------------
__device__ __forceinline__ void gemm_body(const float* __restrict__ X,
                                          const unsigned short* __restrict__ Wfh,
                                          const unsigned short* __restrict__ Wfl,
                                          unsigned short* __restrict__ out16,
                                          int N, int blk,
                                          unsigned short (*Xh)[136],
                                          unsigned short (*Xl)[136]) {
    int tid = threadIdx.x;
    int row0 = blk * 64;
    #pragma unroll
    for (int it = 0; it < 8; ++it) {
        int f = it * 256 + tid;           // 2048 float4 chunks
        int r = f >> 5, c4 = f & 31;
        float4 v = make_float4(0.f, 0.f, 0.f, 0.f);
        int gr = row0 + r;
        if (gr < N) v = *(const float4*)(X + (size_t)gr * 128 + c4 * 4);
        float vv[4] = {v.x, v.y, v.z, v.w};
        Pack8 h, l;
        #pragma unroll
        for (int j = 0; j < 4; ++j) {
            h.s[j] = f2bf(vv[j]);
            float rr = vv[j] - bf2f(h.s[j]);
            l.s[j] = f2bf(rr);
        }
        *(uint2*)(&Xh[r][c4 * 4]) = h.u;
        *(uint2*)(&Xl[r][c4 * 4]) = l.u;
    }
    __syncthreads();

    int lane = tid & 63;
    int wv = tid >> 6;
    int quad = lane >> 4, nlo = lane & 15;
    f32x4 acc[8];
    #pragma unroll
    for (int t = 0; t < 8; ++t) acc[t] = (f32x4){0.f, 0.f, 0.f, 0.f};

    #pragma unroll
    for (int ks = 0; ks < 4; ++ks) {
        int kcol = ks * 32 + quad * 8;
        Frag16 xh, xl;
        xh.u = *(const uint4*)(&Xh[wv * 16 + nlo][kcol]);
        xl.u = *(const uint4*)(&Xl[wv * 16 + nlo][kcol]);
        #pragma unroll
        for (int t = 0; t < 8; ++t) {
            size_t cidx = ((size_t)(t * 4 + ks) * 64 + lane) * 8;
            Frag16 wh, wl;
            wh.u = *(const uint4*)(Wfh + cidx);
            wl.u = *(const uint4*)(Wfl + cidx);
            acc[t] = __builtin_amdgcn_mfma_f32_16x16x32_bf16(xh.f, wh.f, acc[t], 0, 0, 0);
            acc[t] = __builtin_amdgcn_mfma_f32_16x16x32_bf16(xh.f, wl.f, acc[t], 0, 0, 0);
            acc[t] = __builtin_amdgcn_mfma_f32_16x16x32_bf16(xl.f, wh.f, acc[t], 0, 0, 0);
        }
    }
    // C/D layout: col = lane&15, row = quad*4 + reg.  col = t*16 + nlo;
    // quarter q = t>>1, within-quarter col = (t&1)*16 + nlo.
    #pragma unroll
    for (int rg = 0; rg < 4; ++rg) {
        int gr = row0 + wv * 16 + quad * 4 + rg;
        if (gr < N) {
            #pragma unroll
            for (int t = 0; t < 8; ++t)
                out16[((size_t)(t >> 1) * N + gr) * 32 + (t & 1) * 16 + nlo] =
                    f2bf(acc[t][rg]);
        }
    }
}

// ---------------------------------------------------------------------------
// FAT kernel: blocks [0,Ggemm) do layer-1 GEMM (x@W1 -> A16); the rest do the
// sharded degree count (atomics). Independent inputs; pipes overlap per CU.
// ---------------------------------------------------------------------------
__global__ __launch_bounds__(256) void fat_kernel(const float* __restrict__ X,
                                                  const unsigned short* __restrict__ Wfh,
                                                  const unsigned short* __restrict__ Wfl,
                                                  unsigned short* __restrict__ out16,
                                                  int N, int Ggemm,
                                                  const int* __restrict__ edges,
                                                  const int* __restrict__ flag,
                                                  int* __restrict__ counts_sh,
                                                  int* __restrict__ rank, int E) {
    __shared__ unsigned short Xh[64][136];   // +8 pad: 2-way conflicts only
    __shared__ unsigned short Xl[64][136];
    if (blockIdx.x < (unsigned)Ggemm) {
        gemm_body(X, Wfh, Wfl, out16, N, blockIdx.x, Xh, Xl);
        return;
    }
    int e = (blockIdx.x - Ggemm) * 256 + threadIdx.x;
    if (e >= E) return;
    int f = *flag;
    int d = load_dst(edges, f, E, e);
    int s = blockIdx.x & 7;
    int r = atomicAdd(&counts_sh[s * N + d], 1);
    rank[e] = (r << 3) | s;
}

// ---------------------------------------------------------------------------
// Layer-2 GEMM, bf16 input: A-fragments loaded DIRECTLY from global (quarter-
// blocked rows: frag at ks*32+quad*8 never crosses a 32-feature boundary, so
// the read is a single uint4 from slab ks).  No LDS.  W2 stays hi/lo split.
// Output A16 is quarter-blocked again for the final aggregation.
// ---------------------------------------------------------------------------
__global__ __launch_bounds__(256) void gemm_h1_kernel(const unsigned short* __restrict__ H1,
                                                      const unsigned short* __restrict__ Wfh,
                                                      const unsigned short* __restrict__ Wfl,
                                                      unsigned short* __restrict__ out16,
                                                      int N) {
    int tid = threadIdx.x;
    int lane = tid & 63, wv = tid >> 6;
    int quad = lane >> 4, nlo = lane & 15;
    int row0 = blockIdx.x * 64 + wv * 16;
    int arow = min(row0 + nlo, N - 1);        // clamp; OOB rows never stored
    Frag16 xa[4];
    #pragma unroll
    for (int ks = 0; ks < 4; ++ks)
        xa[ks].u = *(const uint4*)(H1 + ((size_t)ks * N + arow) * 32 + quad * 8);

    f32x4 acc[8];
    #pragma unroll
    for (int t = 0; t < 8; ++t) acc[t] = (f32x4){0.f, 0.f, 0.f, 0.f};

    #pragma unroll
    for (int ks = 0; ks < 4; ++ks) {
        #pragma unroll
        for (int t = 0; t < 8; ++t) {
            size_t cidx = ((size_t)(t * 4 + ks) * 64 + lane) * 8;
            Frag16 wh, wl;
            wh.u = *(const uint4*)(Wfh + cidx);
            wl.u = *(const uint4*)(Wfl + cidx);
            acc[t] = __builtin_amdgcn_mfma_f32_16x16x32_bf16(xa[ks].f, wh.f, acc[t], 0, 0, 0);
            acc[t] = __builtin_amdgcn_mfma_f32_16x16x32_bf16(xa[ks].f, wl.f, acc[t], 0, 0, 0);
        }
    }
    #pragma unroll
    for (int rg = 0; rg < 4; ++rg) {
        int gr = row0 + quad * 4 + rg;
        if (gr < N) {
            #pragma unroll
            for (int t = 0; t < 8; ++t)
                out16[((size_t)(t >> 1) * N + gr) * 32 + (t & 1) * 16 + nlo] =
                    f2bf(acc[t][rg]);
        }
    }
}

// ---------------------------------------------------------------------------
// merge_dis: shard counts -> shard base offsets (in place), degree -> counts,
// dis = rsqrt(deg+1); per-1024-node sums -> bsum.
// ---------------------------------------------------------------------------
__global__ __launch_bounds__(256) void merge_dis_kernel(int* __restrict__ counts_sh,
                                                        int* __restrict__ counts,
                                                        float* __restrict__ dis,
                                                        int* __restrict__ bsum, int N) {
    __shared__ int red[4];
    int tid = threadIdx.x;
    int bs = 0;
    #pragma unroll
    for (int j = 0; j < 4; ++j) {
        int d = blockIdx.x * 1024 + j * 256 + tid;
        if (d < N) {
            int run = 0;
            #pragma unroll
            for (int s = 0; s < 8; ++s) {
                int v = counts_sh[s * N + d];
                counts_sh[s * N + d] = run;
                run += v;
            }
            counts[d] = run;
            dis[d] = rsqrtf((float)(run + 1));
            bs += run;
        }
    }
    #pragma unroll
    for (int off = 32; off >= 1; off >>= 1) bs += __shfl_down(bs, off, 64);
    if ((tid & 63) == 0) red[tid >> 6] = bs;
    __syncthreads();
    if (tid == 0) bsum[blockIdx.x] = red[0] + red[1] + red[2] + red[3];
}

__global__ void scan2_kernel(const int* __restrict__ bsum, int* __restrict__ boff,
                             int B, int* __restrict__ row_ptr, int N, int E) {
    int lane = threadIdx.x;
    int carry = 0;
    for (int base = 0; base < B; base += 64) {
        int i = base + lane;
        int v = (i < B) ? bsum[i] : 0;
        int x = v;
        #pragma unroll
        for (int off = 1; off < 64; off <<= 1) {
            int t = __shfl_up(x, off, 64);
            if (lane >= off) x += t;
        }
        if (i < B) boff[i] = carry + x - v;
        carry += __shfl(x, 63, 64);
    }
    if (lane == 0) row_ptr[N] = E;
}

__global__ __launch_bounds__(256) void scan3_kernel(const int* __restrict__ counts,
                                                    const int* __restrict__ boff,
                                                    int* __restrict__ row_ptr, int N) {
    __shared__ int wsum[4];
    int tid = threadIdx.x;
    int lane = tid & 63, wv = tid >> 6;
    int base = blockIdx.x * 1024 + tid * 4;
    int c[4];
    #pragma unroll
    for (int j = 0; j < 4; ++j) c[j] = (base + j < N) ? counts[base + j] : 0;
    int tsum = c[0] + c[1] + c[2] + c[3];
    int x = tsum;
    #pragma unroll
    for (int off = 1; off < 64; off <<= 1) {
        int t = __shfl_up(x, off, 64);
        if (lane >= off) x += t;
    }
    int texcl = x - tsum;
    if (lane == 63) wsum[wv] = x;
    __syncthreads();
    int woff = 0;
    for (int w = 0; w < wv; ++w) woff += wsum[w];
    int off0 = boff[blockIdx.x] + woff + texcl;
    int run = 0;
    #pragma unroll
    for (int j = 0; j < 4; ++j) {
        if (base + j < N) row_ptr[base + j] = off0 + run;
        run += c[j];
    }
}

// CSR fill (atomic-free): pos = row_ptr[d] + shard_base + local_rank.
__global__ void fill_kernel(const int* __restrict__ edges, const int* __restrict__ flag,
                            const int* __restrict__ row_ptr, const int* __restrict__ rank,
                            const int* __restrict__ counts_sh,
                            const float* __restrict__ dis, int2* __restrict__ edata,
                            int E, int N) {
    int e = blockIdx.x * blockDim.x + threadIdx.x;
    if (e >= E) return;
    int f = *flag;
    int s = load_src(edges, f, E, e);
    int d = load_dst(edges, f, E, e);
    int rk = rank[e];
    int sh = rk & 7;
    int pos = row_ptr[d] + counts_sh[sh * N + d] + (rk >> 3);
    edata[pos] = make_int2(s, __float_as_int(dis[s]));
}

// ---------------------------------------------------------------------------
// Aggregation, QUARTER-SPLIT for L2 residency: grid is quarter-major
// (q = blockIdx.x / Bq); each pass gathers a contiguous [N][32]-feature slab
// (3.2 MB @ N=50K -> fits a 4 MiB per-XCD L2).  Wave = 1 (node, quarter):
// 4 edge-groups x 16 feature-lanes; each gather instruction covers 4 edges
// x 64B (same 256B/instr as the old full-row gather).  Cross-group combine
// via 2 shfl_xor adds.  BF16OUT: quarter-blocked bf16 (inter-layer) or
// standard-layout fp32 (final output).
// ---------------------------------------------------------------------------
template <bool BF16OUT>
__global__ __launch_bounds__(256) void agg_kernel(const unsigned short* __restrict__ H16,
                                                  const int* __restrict__ row_ptr,
                                                  const int2* __restrict__ edata,
                                                  const float* __restrict__ dis,
                                                  const float* __restrict__ bias,
                                                  void* __restrict__ outp, int N, int Bq) {
    int q   = blockIdx.x / Bq;                 // quarter-major block order
    int bi  = blockIdx.x - q * Bq;
    int wv  = threadIdx.x >> 6;
    int lane = threadIdx.x & 63;
    int wid = bi * 4 + wv;
    if (wid >= N) return;
    int g = lane >> 4, fl = lane & 15;         // edge-group, feature-lane
    int q16 = q * 16;
    const ushort2* H2 = (const ushort2*)H16;   // quarter-blocked [4][N][16]
    float dd = dis[wid];
    ushort2 hv = H2[((size_t)q * N + wid) * 16 + fl];
    float ws = (g == 0) ? dd * dd : 0.f;       // self term in group 0 only
    float2 acc = make_float2(bf2f(hv.x) * ws, bf2f(hv.y) * ws);
    int e0 = __builtin_amdgcn_readfirstlane(row_ptr[wid]);
    int e1 = __builtin_amdgcn_readfirstlane(row_ptr[wid + 1]);
    for (int base = e0; base < e1; base += 8) {
        int ea = base + g;                     // groups cover edata[base..base+7]
        int eb = base + 4 + g;                 // (contiguous 64B across the wave)
        bool va = ea < e1, vb = eb < e1;
        int2 eda = edata[va ? ea : base];
        int2 edb = edata[vb ? eb : base];
        float wa = va ? __int_as_float(eda.y) * dd : 0.f;
        float wb = vb ? __int_as_float(edb.y) * dd : 0.f;
        ushort2 ha = H2[((size_t)q * N + eda.x) * 16 + fl];
        ushort2 hb = H2[((size_t)q * N + edb.x) * 16 + fl];
        acc.x += bf2f(ha.x) * wa;
        acc.y += bf2f(ha.y) * wa;
        acc.x += bf2f(hb.x) * wb;
        acc.y += bf2f(hb.y) * wb;
    }
    // combine the 4 edge-groups (feature-lane fl is preserved by xor 16/32)
    acc.x += __shfl_xor(acc.x, 16, 64);
    acc.y += __shfl_xor(acc.y, 16, 64);
    acc.x += __shfl_xor(acc.x, 32, 64);
    acc.y += __shfl_xor(acc.y, 32, 64);
    if (g != 0) return;
    float2 b = ((const float2*)bias)[q16 + fl];
    float ox = fmaxf(acc.x + b.x, 0.f);
    float oy = fmaxf(acc.y + b.y, 0.f);
    if (BF16OUT) {
        ((ushort2*)outp)[((size_t)q * N + wid) * 16 + fl] =
            make_ushort2(f2bf(ox), f2bf(oy));
    } else {
        ((float2*)outp)[(size_t)wid * 64 + q16 + fl] = make_float2(ox, oy);
    }
}

extern "C" void kernel_launch(void* const* d_in, const int* in_sizes, int n_in,
                              void* d_out, int out_size, void* d_ws, size_t ws_size,
                              hipStream_t stream) {
    const float* x    = (const float*)d_in[0];
    const int*  edges = (const int*)d_in[1];
    const float* W1   = (const float*)d_in[2];
    const float* b1   = (const float*)d_in[3];
    const float* W2   = (const float*)d_in[4];
    const float* b2   = (const float*)d_in[5];
    float* out = (float*)d_out;

    const int F = 128;
    const int N = in_sizes[0] / F;
    const int E = in_sizes[1] / 2;
    const int NB = CDIV(N, 1024);          // scan blocks (<=64)
    const int Ggemm = CDIV(N, 64);
    const int Gcount = CDIV(E, 256);

    #define AL4(v) (((v) + 3) & ~3)        // keep segments 16B-aligned
    unsigned short* A16 = (unsigned short*)d_ws;            // N*128 bf16 (gemm1 out; reused for h1@W2), quarter-blocked
    unsigned short* H1  = A16 + (size_t)AL4(N * F);         // N*128 bf16 (agg1 out), quarter-blocked
    float* dis      = (float*)(H1 + (size_t)AL4(N * F));    // N
    int*  counts    = (int*)(dis + AL4(N));                 // N
    int*  counts_sh = counts + AL4(N);                      // 8N  } zeroed by prep
    int*  flag      = counts_sh + AL4(8 * N);               // 4   } zeroed by prep blk2
    int*  row_ptr   = flag + 4;                             // N+4
    int*  bsum      = row_ptr + AL4(N + 1);                 // 64
    int*  boff      = bsum + 64;                            // 64
    int*  rank      = boff + 64;                            // E
    int2* edata     = (int2*)(rank + AL4(E));               // E
    unsigned short* Wf1h = (unsigned short*)(edata + E);    // 16384 each
    unsigned short* Wf1l = Wf1h + 16384;
    unsigned short* Wf2h = Wf1l + 16384;
    unsigned short* Wf2l = Wf2h + 16384;

    const int Z4 = AL4(8 * N) / 4;         // int4s of counts_sh to zero
    const int Gprep = 3 + CDIV(Z4, 256);
    const int Bq = CDIV(N, 4);             // blocks per quarter (4 nodes/block)

    prep_kernel<<<Gprep, 256, 0, stream>>>(W1, W2, Wf1h, Wf1l, Wf2h, Wf2l,
                                           edges, flag, E, (int4*)counts_sh, Z4);
    fat_kernel<<<Ggemm + Gcount, 256, 0, stream>>>(x, Wf1h, Wf1l, A16, N, Ggemm,
                                                   edges, flag, counts_sh, rank, E);
    merge_dis_kernel<<<NB, 256, 0, stream>>>(counts_sh, counts, dis, bsum, N);
    scan2_kernel<<<1, 64, 0, stream>>>(bsum, boff, NB, row_ptr, N, E);
    scan3_kernel<<<NB, 256, 0, stream>>>(counts, boff, row_ptr, N);
    fill_kernel<<<Gcount, 256, 0, stream>>>(edges, flag, row_ptr, rank,
                                            counts_sh, dis, edata, E, N);

    agg_kernel<true><<<4 * Bq, 256, 0, stream>>>(A16, row_ptr, edata, dis, b1, H1, N, Bq);
    gemm_h1_kernel<<<CDIV(N, 64), 256, 0, stream>>>(H1, Wf2h, Wf2l, A16, N);
    agg_kernel<false><<<4 * Bq, 256, 0, stream>>>(A16, row_ptr, edata, dis, b2, out, N, Bq);
}

// Round 2
// 217.243 us; speedup vs baseline: 1.4725x; 1.4725x over previous
//
#include <hip/hip_runtime.h>
#include <hip/hip_bf16.h>

#define CDIV(a,b) (((a)+(b)-1)/(b))

typedef __bf16 bf16x8 __attribute__((ext_vector_type(8)));
typedef float  f32x4  __attribute__((ext_vector_type(4)));

union Frag16 { uint4 u; bf16x8 f; unsigned short s[8]; };
union Pack8  { unsigned short s[4]; uint2 u; };

__device__ __forceinline__ unsigned short f2bf(float f) {   // fp32 -> bf16 RNE
    unsigned u = __float_as_uint(f);
    return (unsigned short)((u + 0x7fff + ((u >> 16) & 1)) >> 16);
}
__device__ __forceinline__ float bf2f(unsigned short s) {
    return __uint_as_float(((unsigned)s) << 16);
}

__device__ __forceinline__ int load_src(const int* e, int f, int E, int i) {
    return f ? e[i] : e[2 * i];
}
__device__ __forceinline__ int load_dst(const int* e, int f, int E, int i) {
    return f ? e[E + i] : e[2 * (E + i)];
}

// ---------------------------------------------------------------------------
// prep: blocks 0,1 swizzle W1/W2 -> hi/lo bf16 MFMA B-fragments; block 2
// zeroes flag then samples edge layout (int64 LE => odd words all zero);
// blocks >=3 zero counts_sh (replaces the hipMemsetAsync dispatch).
// Fragment order: chunk c=(ntile*4+ks)*64+lane, 8 bf16:
//   B[k = ks*32 + (lane>>4)*8 + j][n = ntile*16 + (lane&15)]
// ---------------------------------------------------------------------------
__global__ __launch_bounds__(256) void prep_kernel(const float* __restrict__ W1,
                                                   const float* __restrict__ W2,
                                                   unsigned short* __restrict__ Wf1h,
                                                   unsigned short* __restrict__ Wf1l,
                                                   unsigned short* __restrict__ Wf2h,
                                                   unsigned short* __restrict__ Wf2l,
                                                   const int* __restrict__ edges,
                                                   int* __restrict__ flag, int E,
                                                   int4* __restrict__ zero_base, int Z4) {
    int tid = threadIdx.x;
    if (blockIdx.x == 2) {
        if (tid == 0) *flag = 0;
        __syncthreads();
        int n = min(E, 4096);
        int found = 0;
        for (int j = tid; j < n; j += 256) found |= (edges[2 * j + 1] != 0);
        if (found) *flag = 1;   // benign race within block
        return;
    }
    if (blockIdx.x >= 3) {
        int idx = (blockIdx.x - 3) * 256 + tid;
        if (idx < Z4) zero_base[idx] = make_int4(0, 0, 0, 0);
        return;
    }
    const float* W = (blockIdx.x == 0) ? W1 : W2;
    unsigned short* Wfh = (blockIdx.x == 0) ? Wf1h : Wf2h;
    unsigned short* Wfl = (blockIdx.x == 0) ? Wf1l : Wf2l;
    #pragma unroll
    for (int it = 0; it < 8; ++it) {
        int c = it * 256 + tid;           // chunk in [0, 2048)
        int ntk = c >> 6;
        int lane = c & 63;
        int ks = ntk & 3;
        int ntile = ntk >> 2;
        int quad = lane >> 4, nlo = lane & 15;
        int n = ntile * 16 + nlo;
        Frag16 h, l;
        #pragma unroll
        for (int j = 0; j < 8; ++j) {
            float w = W[(ks * 32 + quad * 8 + j) * 128 + n];
            h.s[j] = f2bf(w);
            float rr = w - bf2f(h.s[j]);
            l.s[j] = f2bf(rr);
        }
        *(uint4*)(Wfh + (size_t)c * 8) = h.u;
        *(uint4*)(Wfl + (size_t)c * 8) = l.u;
    }
}

// ---------------------------------------------------------------------------
// Split-bf16 MFMA GEMM body (fp32 input): out16 = bf16( X @ W ), fp32-accurate
// via xh*wh + xh*wl + xl*wh.  64 rows/block, 4 waves.  Row-major C-write.
// ---------------------------------------------------------------------------
__device__ __forceinline__ void gemm_body(const float* __restrict__ X,
                                          const unsigned short* __restrict__ Wfh,
                                          const unsigned short* __restrict__ Wfl,
                                          unsigned short* __restrict__ out16,
                                          int N, int blk,
                                          unsigned short (*Xh)[136],
                                          unsigned short (*Xl)[136]) {
    int tid = threadIdx.x;
    int row0 = blk * 64;
    #pragma unroll
    for (int it = 0; it < 8; ++it) {
        int f = it * 256 + tid;           // 2048 float4 chunks
        int r = f >> 5, c4 = f & 31;
        float4 v = make_float4(0.f, 0.f, 0.f, 0.f);
        int gr = row0 + r;
        if (gr < N) v = *(const float4*)(X + (size_t)gr * 128 + c4 * 4);
        float vv[4] = {v.x, v.y, v.z, v.w};
        Pack8 h, l;
        #pragma unroll
        for (int j = 0; j < 4; ++j) {
            h.s[j] = f2bf(vv[j]);
            float rr = vv[j] - bf2f(h.s[j]);
            l.s[j] = f2bf(rr);
        }
        *(uint2*)(&Xh[r][c4 * 4]) = h.u;
        *(uint2*)(&Xl[r][c4 * 4]) = l.u;
    }
    __syncthreads();

    int lane = tid & 63;
    int wv = tid >> 6;
    int quad = lane >> 4, nlo = lane & 15;
    f32x4 acc[8];
    #pragma unroll
    for (int t = 0; t < 8; ++t) acc[t] = (f32x4){0.f, 0.f, 0.f, 0.f};

    #pragma unroll
    for (int ks = 0; ks < 4; ++ks) {
        int kcol = ks * 32 + quad * 8;
        Frag16 xh, xl;
        xh.u = *(const uint4*)(&Xh[wv * 16 + nlo][kcol]);
        xl.u = *(const uint4*)(&Xl[wv * 16 + nlo][kcol]);
        #pragma unroll
        for (int t = 0; t < 8; ++t) {
            size_t cidx = ((size_t)(t * 4 + ks) * 64 + lane) * 8;
            Frag16 wh, wl;
            wh.u = *(const uint4*)(Wfh + cidx);
            wl.u = *(const uint4*)(Wfl + cidx);
            acc[t] = __builtin_amdgcn_mfma_f32_16x16x32_bf16(xh.f, wh.f, acc[t], 0, 0, 0);
            acc[t] = __builtin_amdgcn_mfma_f32_16x16x32_bf16(xh.f, wl.f, acc[t], 0, 0, 0);
            acc[t] = __builtin_amdgcn_mfma_f32_16x16x32_bf16(xl.f, wh.f, acc[t], 0, 0, 0);
        }
    }
    // C/D layout: col = lane&15, row = quad*4 + reg
    #pragma unroll
    for (int rg = 0; rg < 4; ++rg) {
        int gr = row0 + wv * 16 + quad * 4 + rg;
        if (gr < N) {
            #pragma unroll
            for (int t = 0; t < 8; ++t)
                out16[(size_t)gr * 128 + t * 16 + nlo] = f2bf(acc[t][rg]);
        }
    }
}

// ---------------------------------------------------------------------------
// FAT kernel: blocks [0,Ggemm) do layer-1 GEMM (x@W1 -> A16); the rest do the
// sharded degree count (atomics). Independent inputs; pipes overlap per CU.
// ---------------------------------------------------------------------------
__global__ __launch_bounds__(256) void fat_kernel(const float* __restrict__ X,
                                                  const unsigned short* __restrict__ Wfh,
                                                  const unsigned short* __restrict__ Wfl,
                                                  unsigned short* __restrict__ out16,
                                                  int N, int Ggemm,
                                                  const int* __restrict__ edges,
                                                  const int* __restrict__ flag,
                                                  int* __restrict__ counts_sh,
                                                  int* __restrict__ rank, int E) {
    __shared__ unsigned short Xh[64][136];   // +8 pad: 2-way conflicts only
    __shared__ unsigned short Xl[64][136];
    if (blockIdx.x < (unsigned)Ggemm) {
        gemm_body(X, Wfh, Wfl, out16, N, blockIdx.x, Xh, Xl);
        return;
    }
    int e = (blockIdx.x - Ggemm) * 256 + threadIdx.x;
    if (e >= E) return;
    int f = *flag;
    int d = load_dst(edges, f, E, e);
    int s = blockIdx.x & 7;
    int r = atomicAdd(&counts_sh[s * N + d], 1);
    rank[e] = (r << 3) | s;
}

// ---------------------------------------------------------------------------
// merge_dis: shard counts -> shard base offsets (in place), degree -> counts,
// dis = rsqrt(deg+1); per-1024-node sums -> bsum.
// ---------------------------------------------------------------------------
__global__ __launch_bounds__(256) void merge_dis_kernel(int* __restrict__ counts_sh,
                                                        int* __restrict__ counts,
                                                        float* __restrict__ dis,
                                                        int* __restrict__ bsum, int N) {
    __shared__ int red[4];
    int tid = threadIdx.x;
    int bs = 0;
    #pragma unroll
    for (int j = 0; j < 4; ++j) {
        int d = blockIdx.x * 1024 + j * 256 + tid;
        if (d < N) {
            int run = 0;
            #pragma unroll
            for (int s = 0; s < 8; ++s) {
                int v = counts_sh[s * N + d];
                counts_sh[s * N + d] = run;
                run += v;
            }
            counts[d] = run;
            dis[d] = rsqrtf((float)(run + 1));
            bs += run;
        }
    }
    #pragma unroll
    for (int off = 32; off >= 1; off >>= 1) bs += __shfl_down(bs, off, 64);
    if ((tid & 63) == 0) red[tid >> 6] = bs;
    __syncthreads();
    if (tid == 0) bsum[blockIdx.x] = red[0] + red[1] + red[2] + red[3];
}

__global__ void scan2_kernel(const int* __restrict__ bsum, int* __restrict__ boff,
                             int B, int* __restrict__ row_ptr, int N, int E) {
    int lane = threadIdx.x;
    int carry = 0;
    for (int base = 0; base < B; base += 64) {
        int i = base + lane;
        int v = (i < B) ? bsum[i] : 0;
        int x = v;
        #pragma unroll
        for (int off = 1; off < 64; off <<= 1) {
            int t = __shfl_up(x, off, 64);
            if (lane >= off) x += t;
        }
        if (i < B) boff[i] = carry + x - v;
        carry += __shfl(x, 63, 64);
    }
    if (lane == 0) row_ptr[N] = E;
}

__global__ __launch_bounds__(256) void scan3_kernel(const int* __restrict__ counts,
                                                    const int* __restrict__ boff,
                                                    int* __restrict__ row_ptr, int N) {
    __shared__ int wsum[4];
    int tid = threadIdx.x;
    int lane = tid & 63, wv = tid >> 6;
    int base = blockIdx.x * 1024 + tid * 4;
    int c[4];
    #pragma unroll
    for (int j = 0; j < 4; ++j) c[j] = (base + j < N) ? counts[base + j] : 0;
    int tsum = c[0] + c[1] + c[2] + c[3];
    int x = tsum;
    #pragma unroll
    for (int off = 1; off < 64; off <<= 1) {
        int t = __shfl_up(x, off, 64);
        if (lane >= off) x += t;
    }
    int texcl = x - tsum;
    if (lane == 63) wsum[wv] = x;
    __syncthreads();
    int woff = 0;
    for (int w = 0; w < wv; ++w) woff += wsum[w];
    int off0 = boff[blockIdx.x] + woff + texcl;
    int run = 0;
    #pragma unroll
    for (int j = 0; j < 4; ++j) {
        if (base + j < N) row_ptr[base + j] = off0 + run;
        run += c[j];
    }
}

// CSR fill (atomic-free): pos = row_ptr[d] + shard_base + local_rank.
__global__ void fill_kernel(const int* __restrict__ edges, const int* __restrict__ flag,
                            const int* __restrict__ row_ptr, const int* __restrict__ rank,
                            const int* __restrict__ counts_sh,
                            const float* __restrict__ dis, int2* __restrict__ edata,
                            int E, int N) {
    int e = blockIdx.x * blockDim.x + threadIdx.x;
    if (e >= E) return;
    int f = *flag;
    int s = load_src(edges, f, E, e);
    int d = load_dst(edges, f, E, e);
    int rk = rank[e];
    int sh = rk & 7;
    int pos = row_ptr[d] + counts_sh[sh * N + d] + (rk >> 3);
    edata[pos] = make_int2(s, __float_as_int(dis[s]));
}

// ---------------------------------------------------------------------------
// FUSED agg1 + layer-2 GEMM.  16 waves/block, one node per wave (identical
// per-wave gather structure to the verified round-0 agg: full 256B rows,
// bf16x2/lane, 8-edge batches).  Each wave's h1 row (bias1+relu, bf16) goes
// to LDS (XOR-swizzled: short-col ^= (row&7)<<3 kills the 16-way A-frag bank
// conflict).  After one barrier, waves 0..7 compute the 16x128 @ W2 MFMA
// (hi/lo split, same numerics as the old gemm_h1) and write H1 = bf16(h1@W2)
// row-major.  Deletes the gemm_h1 launch and H1's 12.8MB write + 12.8MB read.
// ---------------------------------------------------------------------------
__global__ __launch_bounds__(1024) void agg1_fused_kernel(
        const unsigned short* __restrict__ A16,
        const int* __restrict__ row_ptr,
        const int2* __restrict__ edata,
        const float* __restrict__ dis,
        const float* __restrict__ bias,
        const unsigned short* __restrict__ Wfh,
        const unsigned short* __restrict__ Wfl,
        unsigned short* __restrict__ H1out, int N) {
    __shared__ unsigned short Hl[16][128];
    int wv = threadIdx.x >> 6;
    int lane = threadIdx.x & 63;
    int wid = blockIdx.x * 16 + wv;
    if (wid < N) {
        const ushort2* H2 = (const ushort2*)A16;
        float dd = dis[wid];
        ushort2 hv = H2[(size_t)wid * 64 + lane];
        float wself = dd * dd;
        float2 acc = make_float2(bf2f(hv.x) * wself, bf2f(hv.y) * wself);
        int e0 = __builtin_amdgcn_readfirstlane(row_ptr[wid]);
        int e1 = __builtin_amdgcn_readfirstlane(row_ptr[wid + 1]);
        for (int e = e0; e < e1; e += 8) {
            int rem = e1 - e;
            int   sj[8];
            float wj[8];
            #pragma unroll
            for (int j = 0; j < 8; ++j) {
                bool valid = j < rem;
                int2 ed = edata[valid ? e + j : e];
                sj[j] = ed.x;
                wj[j] = valid ? __int_as_float(ed.y) * dd : 0.f;
            }
            ushort2 aj[8];
            #pragma unroll
            for (int j = 0; j < 8; ++j)
                aj[j] = H2[(size_t)sj[j] * 64 + lane];
            #pragma unroll
            for (int j = 0; j < 8; ++j) {
                acc.x += bf2f(aj[j].x) * wj[j];
                acc.y += bf2f(aj[j].y) * wj[j];
            }
        }
        float2 b = ((const float2*)bias)[lane];
        float ox = fmaxf(acc.x + b.x, 0.f);
        float oy = fmaxf(acc.y + b.y, 0.f);
        // swizzled LDS store: logical short-cols (2*lane, 2*lane+1), row wv
        int c = (lane * 2) ^ ((wv & 7) << 3);
        *(ushort2*)(&Hl[wv][c]) = make_ushort2(f2bf(ox), f2bf(oy));
    }
    __syncthreads();
    if (wv >= 8) return;
    // wave wv owns output n-tile t=wv: cols wv*16 .. wv*16+15
    int quad = lane >> 4, nlo = lane & 15;
    f32x4 acc = (f32x4){0.f, 0.f, 0.f, 0.f};
    #pragma unroll
    for (int ks = 0; ks < 4; ++ks) {
        // A-frag: row m=nlo, logical cols ks*32+quad*8 .. +7 (8-aligned, so the
        // XOR swizzle keeps them contiguous and 16B-aligned)
        int cb = (ks * 32 + quad * 8) ^ ((nlo & 7) << 3);
        Frag16 xa, wh, wl;
        xa.u = *(const uint4*)(&Hl[nlo][cb]);
        size_t cidx = ((size_t)(wv * 4 + ks) * 64 + lane) * 8;
        wh.u = *(const uint4*)(Wfh + cidx);
        wl.u = *(const uint4*)(Wfl + cidx);
        acc = __builtin_amdgcn_mfma_f32_16x16x32_bf16(xa.f, wh.f, acc, 0, 0, 0);
        acc = __builtin_amdgcn_mfma_f32_16x16x32_bf16(xa.f, wl.f, acc, 0, 0, 0);
    }
    #pragma unroll
    for (int rg = 0; rg < 4; ++rg) {
        int gr = blockIdx.x * 16 + quad * 4 + rg;
        if (gr < N)
            H1out[(size_t)gr * 128 + wv * 16 + nlo] = f2bf(acc[rg]);
    }
}

// ---------------------------------------------------------------------------
// Final aggregation (round-0 form): one wave per node, bf16x2 (4B)/lane
// gathers, fp32 accumulate, bias+relu epilogue, fp32 output.
// ---------------------------------------------------------------------------
__global__ __launch_bounds__(256) void agg2_kernel(const unsigned short* __restrict__ H16,
                                                   const int* __restrict__ row_ptr,
                                                   const int2* __restrict__ edata,
                                                   const float* __restrict__ dis,
                                                   const float* __restrict__ bias,
                                                   float* __restrict__ outp, int N) {
    int wid = (blockIdx.x * blockDim.x + threadIdx.x) >> 6;
    int lane = threadIdx.x & 63;
    if (wid >= N) return;
    const ushort2* H2 = (const ushort2*)H16;
    float dd = dis[wid];
    ushort2 hv = H2[(size_t)wid * 64 + lane];
    float wself = dd * dd;
    float2 acc = make_float2(bf2f(hv.x) * wself, bf2f(hv.y) * wself);
    int e0 = __builtin_amdgcn_readfirstlane(row_ptr[wid]);
    int e1 = __builtin_amdgcn_readfirstlane(row_ptr[wid + 1]);
    for (int e = e0; e < e1; e += 8) {
        int rem = e1 - e;
        int   sj[8];
        float wj[8];
        #pragma unroll
        for (int j = 0; j < 8; ++j) {
            bool valid = j < rem;
            int2 ed = edata[valid ? e + j : e];
            sj[j] = ed.x;
            wj[j] = valid ? __int_as_float(ed.y) * dd : 0.f;
        }
        ushort2 aj[8];
        #pragma unroll
        for (int j = 0; j < 8; ++j)
            aj[j] = H2[(size_t)sj[j] * 64 + lane];
        #pragma unroll
        for (int j = 0; j < 8; ++j) {
            acc.x += bf2f(aj[j].x) * wj[j];
            acc.y += bf2f(aj[j].y) * wj[j];
        }
    }
    float2 b = ((const float2*)bias)[lane];
    float ox = fmaxf(acc.x + b.x, 0.f);
    float oy = fmaxf(acc.y + b.y, 0.f);
    ((float2*)outp)[(size_t)wid * 64 + lane] = make_float2(ox, oy);
}

extern "C" void kernel_launch(void* const* d_in, const int* in_sizes, int n_in,
                              void* d_out, int out_size, void* d_ws, size_t ws_size,
                              hipStream_t stream) {
    const float* x    = (const float*)d_in[0];
    const int*  edges = (const int*)d_in[1];
    const float* W1   = (const float*)d_in[2];
    const float* b1   = (const float*)d_in[3];
    const float* W2   = (const float*)d_in[4];
    const float* b2   = (const float*)d_in[5];
    float* out = (float*)d_out;

    const int F = 128;
    const int N = in_sizes[0] / F;
    const int E = in_sizes[1] / 2;
    const int NB = CDIV(N, 1024);          // scan blocks (<=64)
    const int Ggemm = CDIV(N, 64);
    const int Gcount = CDIV(E, 256);

    #define AL4(v) (((v) + 3) & ~3)        // keep segments 16B-aligned
    unsigned short* A16 = (unsigned short*)d_ws;            // N*128 bf16 (gemm1 out; agg1 gather source)
    unsigned short* H1  = A16 + (size_t)AL4(N * F);         // N*128 bf16 (fused agg1+gemm2 out)
    float* dis      = (float*)(H1 + (size_t)AL4(N * F));    // N
    int*  counts    = (int*)(dis + AL4(N));                 // N
    int*  counts_sh = counts + AL4(N);                      // 8N  } zeroed by prep
    int*  flag      = counts_sh + AL4(8 * N);               // 4   } zeroed by prep blk2
    int*  row_ptr   = flag + 4;                             // N+4
    int*  bsum      = row_ptr + AL4(N + 1);                 // 64
    int*  boff      = bsum + 64;                            // 64
    int*  rank      = boff + 64;                            // E
    int2* edata     = (int2*)(rank + AL4(E));               // E
    unsigned short* Wf1h = (unsigned short*)(edata + E);    // 16384 each
    unsigned short* Wf1l = Wf1h + 16384;
    unsigned short* Wf2h = Wf1l + 16384;
    unsigned short* Wf2l = Wf2h + 16384;

    const int Z4 = AL4(8 * N) / 4;         // int4s of counts_sh to zero
    const int Gprep = 3 + CDIV(Z4, 256);

    prep_kernel<<<Gprep, 256, 0, stream>>>(W1, W2, Wf1h, Wf1l, Wf2h, Wf2l,
                                           edges, flag, E, (int4*)counts_sh, Z4);
    fat_kernel<<<Ggemm + Gcount, 256, 0, stream>>>(x, Wf1h, Wf1l, A16, N, Ggemm,
                                                   edges, flag, counts_sh, rank, E);
    merge_dis_kernel<<<NB, 256, 0, stream>>>(counts_sh, counts, dis, bsum, N);
    scan2_kernel<<<1, 64, 0, stream>>>(bsum, boff, NB, row_ptr, N, E);
    scan3_kernel<<<NB, 256, 0, stream>>>(counts, boff, row_ptr, N);
    fill_kernel<<<Gcount, 256, 0, stream>>>(edges, flag, row_ptr, rank,
                                            counts_sh, dis, edata, E, N);

    agg1_fused_kernel<<<CDIV(N, 16), 1024, 0, stream>>>(A16, row_ptr, edata, dis,
                                                        b1, Wf2h, Wf2l, H1, N);
    agg2_kernel<<<CDIV(N * 64, 256), 256, 0, stream>>>(H1, row_ptr, edata, dis, b2, out, N);
}

// Round 3
// 214.074 us; speedup vs baseline: 1.4943x; 1.0148x over previous
//
#include <hip/hip_runtime.h>
#include <hip/hip_bf16.h>

#define CDIV(a,b) (((a)+(b)-1)/(b))

typedef __bf16 bf16x8 __attribute__((ext_vector_type(8)));
typedef float  f32x4  __attribute__((ext_vector_type(4)));

union Frag16 { uint4 u; bf16x8 f; unsigned short s[8]; };
union Pack8  { unsigned short s[4]; uint2 u; };

__device__ __forceinline__ unsigned short f2bf(float f) {   // fp32 -> bf16 RNE
    unsigned u = __float_as_uint(f);
    return (unsigned short)((u + 0x7fff + ((u >> 16) & 1)) >> 16);
}
__device__ __forceinline__ float bf2f(unsigned short s) {
    return __uint_as_float(((unsigned)s) << 16);
}

__device__ __forceinline__ int load_src(const int* e, int f, int E, int i) {
    return f ? e[i] : e[2 * i];
}
__device__ __forceinline__ int load_dst(const int* e, int f, int E, int i) {
    return f ? e[E + i] : e[2 * (E + i)];
}

// ---------------------------------------------------------------------------
// prep: blocks 0,1 swizzle W1/W2 -> hi/lo bf16 MFMA B-fragments; block 2
// zeroes flag then samples edge layout (int64 LE => odd words all zero);
// blocks >=3 zero counts_sh AND bsum (bsum must be re-zeroed every graph
// replay: the fused scan uses flag-bit words in it).
// Fragment order: chunk c=(ntile*4+ks)*64+lane, 8 bf16:
//   B[k = ks*32 + (lane>>4)*8 + j][n = ntile*16 + (lane&15)]
// ---------------------------------------------------------------------------
__global__ __launch_bounds__(256) void prep_kernel(const float* __restrict__ W1,
                                                   const float* __restrict__ W2,
                                                   unsigned short* __restrict__ Wf1h,
                                                   unsigned short* __restrict__ Wf1l,
                                                   unsigned short* __restrict__ Wf2h,
                                                   unsigned short* __restrict__ Wf2l,
                                                   const int* __restrict__ edges,
                                                   int* __restrict__ flag, int E,
                                                   int4* __restrict__ zero_base, int Z4) {
    int tid = threadIdx.x;
    if (blockIdx.x == 2) {
        if (tid == 0) *flag = 0;
        __syncthreads();
        int n = min(E, 4096);
        int found = 0;
        for (int j = tid; j < n; j += 256) found |= (edges[2 * j + 1] != 0);
        if (found) *flag = 1;   // benign race within block
        return;
    }
    if (blockIdx.x >= 3) {
        int idx = (blockIdx.x - 3) * 256 + tid;
        if (idx < Z4) zero_base[idx] = make_int4(0, 0, 0, 0);
        return;
    }
    const float* W = (blockIdx.x == 0) ? W1 : W2;
    unsigned short* Wfh = (blockIdx.x == 0) ? Wf1h : Wf2h;
    unsigned short* Wfl = (blockIdx.x == 0) ? Wf1l : Wf2l;
    #pragma unroll
    for (int it = 0; it < 8; ++it) {
        int c = it * 256 + tid;           // chunk in [0, 2048)
        int ntk = c >> 6;
        int lane = c & 63;
        int ks = ntk & 3;
        int ntile = ntk >> 2;
        int quad = lane >> 4, nlo = lane & 15;
        int n = ntile * 16 + nlo;
        Frag16 h, l;
        #pragma unroll
        for (int j = 0; j < 8; ++j) {
            float w = W[(ks * 32 + quad * 8 + j) * 128 + n];
            h.s[j] = f2bf(w);
            float rr = w - bf2f(h.s[j]);
            l.s[j] = f2bf(rr);
        }
        *(uint4*)(Wfh + (size_t)c * 8) = h.u;
        *(uint4*)(Wfl + (size_t)c * 8) = l.u;
    }
}

// ---------------------------------------------------------------------------
// Split-bf16 MFMA GEMM body (fp32 input): out16 = bf16( X @ W ), fp32-accurate
// via xh*wh + xh*wl + xl*wh.  64 rows/block, 4 waves.  Row-major C-write.
// ---------------------------------------------------------------------------
__device__ __forceinline__ void gemm_body(const float* __restrict__ X,
                                          const unsigned short* __restrict__ Wfh,
                                          const unsigned short* __restrict__ Wfl,
                                          unsigned short* __restrict__ out16,
                                          int N, int blk,
                                          unsigned short (*Xh)[136],
                                          unsigned short (*Xl)[136]) {
    int tid = threadIdx.x;
    int row0 = blk * 64;
    #pragma unroll
    for (int it = 0; it < 8; ++it) {
        int f = it * 256 + tid;           // 2048 float4 chunks
        int r = f >> 5, c4 = f & 31;
        float4 v = make_float4(0.f, 0.f, 0.f, 0.f);
        int gr = row0 + r;
        if (gr < N) v = *(const float4*)(X + (size_t)gr * 128 + c4 * 4);
        float vv[4] = {v.x, v.y, v.z, v.w};
        Pack8 h, l;
        #pragma unroll
        for (int j = 0; j < 4; ++j) {
            h.s[j] = f2bf(vv[j]);
            float rr = vv[j] - bf2f(h.s[j]);
            l.s[j] = f2bf(rr);
        }
        *(uint2*)(&Xh[r][c4 * 4]) = h.u;
        *(uint2*)(&Xl[r][c4 * 4]) = l.u;
    }
    __syncthreads();

    int lane = tid & 63;
    int wv = tid >> 6;
    int quad = lane >> 4, nlo = lane & 15;
    f32x4 acc[8];
    #pragma unroll
    for (int t = 0; t < 8; ++t) acc[t] = (f32x4){0.f, 0.f, 0.f, 0.f};

    #pragma unroll
    for (int ks = 0; ks < 4; ++ks) {
        int kcol = ks * 32 + quad * 8;
        Frag16 xh, xl;
        xh.u = *(const uint4*)(&Xh[wv * 16 + nlo][kcol]);
        xl.u = *(const uint4*)(&Xl[wv * 16 + nlo][kcol]);
        #pragma unroll
        for (int t = 0; t < 8; ++t) {
            size_t cidx = ((size_t)(t * 4 + ks) * 64 + lane) * 8;
            Frag16 wh, wl;
            wh.u = *(const uint4*)(Wfh + cidx);
            wl.u = *(const uint4*)(Wfl + cidx);
            acc[t] = __builtin_amdgcn_mfma_f32_16x16x32_bf16(xh.f, wh.f, acc[t], 0, 0, 0);
            acc[t] = __builtin_amdgcn_mfma_f32_16x16x32_bf16(xh.f, wl.f, acc[t], 0, 0, 0);
            acc[t] = __builtin_amdgcn_mfma_f32_16x16x32_bf16(xl.f, wh.f, acc[t], 0, 0, 0);
        }
    }
    // C/D layout: col = lane&15, row = quad*4 + reg
    #pragma unroll
    for (int rg = 0; rg < 4; ++rg) {
        int gr = row0 + wv * 16 + quad * 4 + rg;
        if (gr < N) {
            #pragma unroll
            for (int t = 0; t < 8; ++t)
                out16[(size_t)gr * 128 + t * 16 + nlo] = f2bf(acc[t][rg]);
        }
    }
}

// ---------------------------------------------------------------------------
// FAT kernel: blocks [0,Ggemm) do layer-1 GEMM (x@W1 -> A16); the rest do the
// sharded degree count (atomics). Independent inputs; pipes overlap per CU.
// ---------------------------------------------------------------------------
__global__ __launch_bounds__(256) void fat_kernel(const float* __restrict__ X,
                                                  const unsigned short* __restrict__ Wfh,
                                                  const unsigned short* __restrict__ Wfl,
                                                  unsigned short* __restrict__ out16,
                                                  int N, int Ggemm,
                                                  const int* __restrict__ edges,
                                                  const int* __restrict__ flag,
                                                  int* __restrict__ counts_sh,
                                                  int* __restrict__ rank, int E) {
    __shared__ unsigned short Xh[64][136];   // +8 pad: 2-way conflicts only
    __shared__ unsigned short Xl[64][136];
    if (blockIdx.x < (unsigned)Ggemm) {
        gemm_body(X, Wfh, Wfl, out16, N, blockIdx.x, Xh, Xl);
        return;
    }
    int e = (blockIdx.x - Ggemm) * 256 + threadIdx.x;
    if (e >= E) return;
    int f = *flag;
    int d = load_dst(edges, f, E, e);
    int s = blockIdx.x & 7;
    int r = atomicAdd(&counts_sh[s * N + d], 1);
    rank[e] = (r << 3) | s;
}

// ---------------------------------------------------------------------------
// FUSED merge + scan (replaces merge_dis, scan2, scan3 — 3 launches -> 1).
// Grid = NB (<=64) blocks, guaranteed co-resident on 256 CUs.  Per block:
//   1. merge the 8 shard counts for its 1024 nodes (exclusive shard bases in
//      place), degree -> dis, accumulate block sum.
//   2. publish block sum as a FLAGGED word (val | 0x40000000, release, agent
//      scope).  Publish strictly precedes any polling => no deadlock.
//   3. wave 0 polls predecessors' flagged words, sums -> block offset.
//   4. intra-block exclusive scan of the 1024 degrees -> row_ptr.
// bsum lives in the prep-zeroed region (stale flags from a prior graph
// replay would otherwise satisfy the poll early).
// ---------------------------------------------------------------------------
#define BSUM_FLAG 0x40000000
__global__ __launch_bounds__(256) void merge_scan_kernel(int* __restrict__ counts_sh,
                                                         float* __restrict__ dis,
                                                         int* __restrict__ bsum,
                                                         int* __restrict__ row_ptr,
                                                         int N, int E) {
    __shared__ int red[4];
    __shared__ int wsum[4];
    __shared__ int boff_sh;
    int tid = threadIdx.x;
    int bid = blockIdx.x;
    if (bid == 0 && tid == 0) row_ptr[N] = E;
    int base = bid * 1024 + tid * 4;
    int cnt[4];
    int bs = 0;
    #pragma unroll
    for (int j = 0; j < 4; ++j) {
        int d = base + j;
        cnt[j] = 0;
        if (d < N) {
            int run = 0;
            #pragma unroll
            for (int s = 0; s < 8; ++s) {
                int v = counts_sh[s * N + d];
                counts_sh[s * N + d] = run;
                run += v;
            }
            cnt[j] = run;
            dis[d] = rsqrtf((float)(run + 1));
            bs += run;
        }
    }
    int t = bs;
    #pragma unroll
    for (int off = 32; off >= 1; off >>= 1) t += __shfl_down(t, off, 64);
    if ((tid & 63) == 0) red[tid >> 6] = t;
    __syncthreads();
    if (tid == 0) {
        int total = red[0] + red[1] + red[2] + red[3];
        __hip_atomic_store(&bsum[bid], total | BSUM_FLAG,
                           __ATOMIC_RELEASE, __HIP_MEMORY_SCOPE_AGENT);
    }
    if (tid < 64) {
        int sum = 0;
        for (int p = tid; p < bid; p += 64) {
            int v;
            do {
                v = __hip_atomic_load(&bsum[p], __ATOMIC_ACQUIRE,
                                      __HIP_MEMORY_SCOPE_AGENT);
                if (!(v & BSUM_FLAG)) __builtin_amdgcn_s_sleep(1);
            } while (!(v & BSUM_FLAG));
            sum += v & (BSUM_FLAG - 1);
        }
        #pragma unroll
        for (int off = 32; off >= 1; off >>= 1) sum += __shfl_down(sum, off, 64);
        if (tid == 0) boff_sh = sum;
    }
    __syncthreads();
    // intra-block exclusive scan (4 contiguous nodes per thread)
    int lane = tid & 63, wv = tid >> 6;
    int tsum = cnt[0] + cnt[1] + cnt[2] + cnt[3];
    int x = tsum;
    #pragma unroll
    for (int off = 1; off < 64; off <<= 1) {
        int u = __shfl_up(x, off, 64);
        if (lane >= off) x += u;
    }
    int texcl = x - tsum;
    if (lane == 63) wsum[wv] = x;
    __syncthreads();
    int woff = 0;
    for (int w = 0; w < wv; ++w) woff += wsum[w];
    int off0 = boff_sh + woff + texcl;
    int run = 0;
    #pragma unroll
    for (int j = 0; j < 4; ++j) {
        if (base + j < N) row_ptr[base + j] = off0 + run;
        run += cnt[j];
    }
}

// CSR fill (atomic-free): pos = row_ptr[d] + shard_base + local_rank.
__global__ void fill_kernel(const int* __restrict__ edges, const int* __restrict__ flag,
                            const int* __restrict__ row_ptr, const int* __restrict__ rank,
                            const int* __restrict__ counts_sh,
                            const float* __restrict__ dis, int2* __restrict__ edata,
                            int E, int N) {
    int e = blockIdx.x * blockDim.x + threadIdx.x;
    if (e >= E) return;
    int f = *flag;
    int s = load_src(edges, f, E, e);
    int d = load_dst(edges, f, E, e);
    int rk = rank[e];
    int sh = rk & 7;
    int pos = row_ptr[d] + counts_sh[sh * N + d] + (rk >> 3);
    edata[pos] = make_int2(s, __float_as_int(dis[s]));
}

// ---------------------------------------------------------------------------
// FUSED agg1 + layer-2 GEMM.  16 waves/block, one node per wave (verified
// round-2 structure: full 256B rows, bf16x2/lane, 8-edge batches).  h1 row
// (bias1+relu, bf16) -> XOR-swizzled LDS; waves 0..7 then do the 16x128 @ W2
// MFMA (hi/lo split) and write H1 row-major.
// ---------------------------------------------------------------------------
__global__ __launch_bounds__(1024) void agg1_fused_kernel(
        const unsigned short* __restrict__ A16,
        const int* __restrict__ row_ptr,
        const int2* __restrict__ edata,
        const float* __restrict__ dis,
        const float* __restrict__ bias,
        const unsigned short* __restrict__ Wfh,
        const unsigned short* __restrict__ Wfl,
        unsigned short* __restrict__ H1out, int N) {
    __shared__ unsigned short Hl[16][128];
    int wv = threadIdx.x >> 6;
    int lane = threadIdx.x & 63;
    int wid = blockIdx.x * 16 + wv;
    if (wid < N) {
        const ushort2* H2 = (const ushort2*)A16;
        float dd = dis[wid];
        ushort2 hv = H2[(size_t)wid * 64 + lane];
        float wself = dd * dd;
        float2 acc = make_float2(bf2f(hv.x) * wself, bf2f(hv.y) * wself);
        int e0 = __builtin_amdgcn_readfirstlane(row_ptr[wid]);
        int e1 = __builtin_amdgcn_readfirstlane(row_ptr[wid + 1]);
        for (int e = e0; e < e1; e += 8) {
            int rem = e1 - e;
            int   sj[8];
            float wj[8];
            #pragma unroll
            for (int j = 0; j < 8; ++j) {
                bool valid = j < rem;
                int2 ed = edata[valid ? e + j : e];
                sj[j] = ed.x;
                wj[j] = valid ? __int_as_float(ed.y) * dd : 0.f;
            }
            ushort2 aj[8];
            #pragma unroll
            for (int j = 0; j < 8; ++j)
                aj[j] = H2[(size_t)sj[j] * 64 + lane];
            #pragma unroll
            for (int j = 0; j < 8; ++j) {
                acc.x += bf2f(aj[j].x) * wj[j];
                acc.y += bf2f(aj[j].y) * wj[j];
            }
        }
        float2 b = ((const float2*)bias)[lane];
        float ox = fmaxf(acc.x + b.x, 0.f);
        float oy = fmaxf(acc.y + b.y, 0.f);
        // swizzled LDS store: logical short-cols (2*lane, 2*lane+1), row wv
        int c = (lane * 2) ^ ((wv & 7) << 3);
        *(ushort2*)(&Hl[wv][c]) = make_ushort2(f2bf(ox), f2bf(oy));
    }
    __syncthreads();
    if (wv >= 8) return;
    // wave wv owns output n-tile t=wv: cols wv*16 .. wv*16+15
    int quad = lane >> 4, nlo = lane & 15;
    f32x4 acc = (f32x4){0.f, 0.f, 0.f, 0.f};
    #pragma unroll
    for (int ks = 0; ks < 4; ++ks) {
        int cb = (ks * 32 + quad * 8) ^ ((nlo & 7) << 3);
        Frag16 xa, wh, wl;
        xa.u = *(const uint4*)(&Hl[nlo][cb]);
        size_t cidx = ((size_t)(wv * 4 + ks) * 64 + lane) * 8;
        wh.u = *(const uint4*)(Wfh + cidx);
        wl.u = *(const uint4*)(Wfl + cidx);
        acc = __builtin_amdgcn_mfma_f32_16x16x32_bf16(xa.f, wh.f, acc, 0, 0, 0);
        acc = __builtin_amdgcn_mfma_f32_16x16x32_bf16(xa.f, wl.f, acc, 0, 0, 0);
    }
    #pragma unroll
    for (int rg = 0; rg < 4; ++rg) {
        int gr = blockIdx.x * 16 + quad * 4 + rg;
        if (gr < N)
            H1out[(size_t)gr * 128 + wv * 16 + nlo] = f2bf(acc[rg]);
    }
}

// ---------------------------------------------------------------------------
// Final aggregation: one wave per node, bf16x2 (4B)/lane gathers, fp32
// accumulate, bias+relu, fp32 output.  Edge batch unrolled x16 (avg degree
// ~16 => most rows finish in ONE batch; 16 gathers in flight per wave for
// latency hiding — VGPR headroom is huge at 12 regs baseline).
// ---------------------------------------------------------------------------
__global__ __launch_bounds__(256) void agg2_kernel(const unsigned short* __restrict__ H16,
                                                   const int* __restrict__ row_ptr,
                                                   const int2* __restrict__ edata,
                                                   const float* __restrict__ dis,
                                                   const float* __restrict__ bias,
                                                   float* __restrict__ outp, int N) {
    int wid = (blockIdx.x * blockDim.x + threadIdx.x) >> 6;
    int lane = threadIdx.x & 63;
    if (wid >= N) return;
    const ushort2* H2 = (const ushort2*)H16;
    float dd = dis[wid];
    ushort2 hv = H2[(size_t)wid * 64 + lane];
    float wself = dd * dd;
    float2 acc = make_float2(bf2f(hv.x) * wself, bf2f(hv.y) * wself);
    int e0 = __builtin_amdgcn_readfirstlane(row_ptr[wid]);
    int e1 = __builtin_amdgcn_readfirstlane(row_ptr[wid + 1]);
    for (int e = e0; e < e1; e += 16) {
        int rem = e1 - e;
        int   sj[16];
        float wj[16];
        #pragma unroll
        for (int j = 0; j < 16; ++j) {
            bool valid = j < rem;
            int2 ed = edata[valid ? e + j : e];
            sj[j] = ed.x;
            wj[j] = valid ? __int_as_float(ed.y) * dd : 0.f;
        }
        ushort2 aj[16];
        #pragma unroll
        for (int j = 0; j < 16; ++j)
            aj[j] = H2[(size_t)sj[j] * 64 + lane];
        #pragma unroll
        for (int j = 0; j < 16; ++j) {
            acc.x += bf2f(aj[j].x) * wj[j];
            acc.y += bf2f(aj[j].y) * wj[j];
        }
    }
    float2 b = ((const float2*)bias)[lane];
    float ox = fmaxf(acc.x + b.x, 0.f);
    float oy = fmaxf(acc.y + b.y, 0.f);
    ((float2*)outp)[(size_t)wid * 64 + lane] = make_float2(ox, oy);
}

extern "C" void kernel_launch(void* const* d_in, const int* in_sizes, int n_in,
                              void* d_out, int out_size, void* d_ws, size_t ws_size,
                              hipStream_t stream) {
    const float* x    = (const float*)d_in[0];
    const int*  edges = (const int*)d_in[1];
    const float* W1   = (const float*)d_in[2];
    const float* b1   = (const float*)d_in[3];
    const float* W2   = (const float*)d_in[4];
    const float* b2   = (const float*)d_in[5];
    float* out = (float*)d_out;

    const int F = 128;
    const int N = in_sizes[0] / F;
    const int E = in_sizes[1] / 2;
    const int NB = CDIV(N, 1024);          // scan blocks (<=64)
    const int Ggemm = CDIV(N, 64);
    const int Gcount = CDIV(E, 256);

    #define AL4(v) (((v) + 3) & ~3)        // keep segments 16B-aligned
    unsigned short* A16 = (unsigned short*)d_ws;            // N*128 bf16 (gemm1 out; agg1 gather source)
    unsigned short* H1  = A16 + (size_t)AL4(N * F);         // N*128 bf16 (fused agg1+gemm2 out)
    float* dis      = (float*)(H1 + (size_t)AL4(N * F));    // N
    int*  counts_sh = (int*)(dis + AL4(N));                 // 8N  } zeroed by prep
    int*  bsum      = counts_sh + AL4(8 * N);               // 64  } zeroed by prep
    int*  flag      = bsum + 64;                            // 4   } zeroed by prep blk2
    int*  row_ptr   = flag + 4;                             // N+4
    int*  rank      = row_ptr + AL4(N + 1);                 // E
    int2* edata     = (int2*)(rank + AL4(E));               // E
    unsigned short* Wf1h = (unsigned short*)(edata + E);    // 16384 each
    unsigned short* Wf1l = Wf1h + 16384;
    unsigned short* Wf2h = Wf1l + 16384;
    unsigned short* Wf2l = Wf2h + 16384;

    const int Z4 = (AL4(8 * N) + 64) / 4;  // int4s: counts_sh + bsum
    const int Gprep = 3 + CDIV(Z4, 256);

    prep_kernel<<<Gprep, 256, 0, stream>>>(W1, W2, Wf1h, Wf1l, Wf2h, Wf2l,
                                           edges, flag, E, (int4*)counts_sh, Z4);
    fat_kernel<<<Ggemm + Gcount, 256, 0, stream>>>(x, Wf1h, Wf1l, A16, N, Ggemm,
                                                   edges, flag, counts_sh, rank, E);
    merge_scan_kernel<<<NB, 256, 0, stream>>>(counts_sh, dis, bsum, row_ptr, N, E);
    fill_kernel<<<Gcount, 256, 0, stream>>>(edges, flag, row_ptr, rank,
                                            counts_sh, dis, edata, E, N);

    agg1_fused_kernel<<<CDIV(N, 16), 1024, 0, stream>>>(A16, row_ptr, edata, dis,
                                                        b1, Wf2h, Wf2l, H1, N);
    agg2_kernel<<<CDIV(N * 64, 256), 256, 0, stream>>>(H1, row_ptr, edata, dis, b2, out, N);
}